// Round 8
// baseline (347.783 us; speedup 1.0000x reference)
//
#include <hip/hip_runtime.h>
#include <hip/hip_bf16.h>

#define C_ 256
#define H_ 64
#define W_ 64
#define N_ 16
#define HW_ 4096
#define IMG_ (C_ * HW_)          // 1048576 elems (fp32 image)
#define PADIMG_ (66 * 66 * 256)  // 1115136 shorts per padded NHWC image
#define WT_ELEMS_ (9 * 16 * 256 * 16)

typedef short bf16x8 __attribute__((ext_vector_type(8)));
typedef float f32x16 __attribute__((ext_vector_type(16)));

__device__ __forceinline__ unsigned short f2bf(float f) {
  __hip_bfloat16 h = __float2bfloat16(f);  // RTNE
  return *reinterpret_cast<unsigned short*>(&h);
}

__device__ __forceinline__ void gld_lds16(const void* g, void* l) {
  __builtin_amdgcn_global_load_lds(
      (const __attribute__((address_space(1))) void*)g,
      (__attribute__((address_space(3))) void*)l, 16, 0, 0);
}

// ---------------------------------------------------------------------------
// Fused x->padded-NHWC-bf16 transform + mask logits (fp64, sign-exact).
// Also zeroes this image's Xp halo (disjoint regions across blocks).
// ---------------------------------------------------------------------------
__global__ __launch_bounds__(256) void xpadmask_kernel(
    const float* __restrict__ x, const float* __restrict__ wm,
    const float* __restrict__ bm, short* __restrict__ Xp,
    unsigned char* __restrict__ mask) {
  __shared__ unsigned short lds[64 * 260];
  __shared__ float wms[256];
  __shared__ double sums[4][64];
  const int h = blockIdx.x, img = blockIdx.y;
  const int tid = threadIdx.x;
  const int wv = tid >> 6, wl = tid & 63;
  wms[tid] = wm[tid];
  __syncthreads();
  const float* xi = x + (size_t)img * IMG_ + h * 64;
  double a0 = 0.0, a1 = 0.0, a2 = 0.0, a3 = 0.0;
#pragma unroll 4
  for (int i = 0; i < 16; ++i) {
#pragma unroll
    for (int u = 0; u < 4; ++u) {
      int c = (i * 4 + u) * 4 + wv;
      float v = xi[(size_t)c * HW_ + wl];
      lds[wl * 260 + c] = f2bf(v);
      double p = (double)v * (double)wms[c];
      if (u == 0) a0 += p;
      else if (u == 1) a1 += p;
      else if (u == 2) a2 += p;
      else a3 += p;
    }
  }
  sums[wv][wl] = (a0 + a1) + (a2 + a3);
  __syncthreads();
  short* Xpimg = Xp + (size_t)img * PADIMG_;
  short* Xpi = Xpimg + ((h + 1) * 66 + 1) * 256;
#pragma unroll
  for (int j = 0; j < 16; ++j) {
    int w = j * 4 + wv;
    int c4 = wl * 4;
    uint2 d = *(const uint2*)&lds[w * 260 + c4];
    *(uint2*)&Xpi[(size_t)w * 256 + c4] = d;
  }
  // Xp halo: left/right columns of this padded row.
  if (tid < 128) {
    const int side = tid >> 6;    // 0 -> col 0, 1 -> col 65
    const int e = (tid & 63) * 4;
    *(uint2*)&Xpimg[((size_t)(h + 1) * 66 + side * 65) * 256 + e] =
        make_uint2(0u, 0u);
  }
  // Xp halo: full top/bottom padded rows.
  if (h == 0 || h == 63) {
    uint2* rowp = (uint2*)(Xpimg + (size_t)((h == 0) ? 0 : 65) * 66 * 256);
    for (int o = tid; o < 66 * 256 / 4; o += 256) rowp[o] = make_uint2(0u, 0u);
  }
  if (wv == 0) {
    double t = sums[0][wl] + sums[1][wl] + sums[2][wl] + sums[3][wl] +
               (double)bm[0];
    mask[img * HW_ + h * 64 + wl] = (t > 0.0) ? 1 : 0;
  }
}

// ---------------------------------------------------------------------------
// Weight transform: Wt[t][kc][k][c16] = bf16(w[k][kc*16+c16][t])
// ---------------------------------------------------------------------------
__global__ __launch_bounds__(256) void wt_kernel(
    const float* __restrict__ w1, const float* __restrict__ w2,
    short* __restrict__ Wt1, short* __restrict__ Wt2) {
  const int k = blockIdx.x, c = threadIdx.x;
  const float* src = blockIdx.y ? w2 : w1;
  short* dst = blockIdx.y ? Wt2 : Wt1;
  const float* s = src + ((size_t)k * 256 + c) * 9;
  const int kc = c >> 4, ce = c & 15;
#pragma unroll
  for (int t = 0; t < 9; ++t)
    dst[(((size_t)t * 16 + kc) * 256 + k) * 16 + ce] = (short)f2bf(s[t]);
}

// ---------------------------------------------------------------------------
// Zero the padded halo (rows 0,65; cols 0,65) of Hp (Xp handled in xpadmask).
// ---------------------------------------------------------------------------
__global__ __launch_bounds__(128) void halo_zero(short* __restrict__ Hp) {
  int p = blockIdx.x;  // 0..259 halo pixel id
  int r, c;
  if (p < 66) { r = 0; c = p; }
  else if (p < 132) { r = 65; c = p - 66; }
  else if (p < 196) { r = p - 131; c = 0; }
  else { r = p - 195; c = 65; }
  unsigned int* d = (unsigned int*)(Hp + (size_t)blockIdx.y * PADIMG_ +
                                    (size_t)(r * 66 + c) * 256);
  d[threadIdx.x] = 0u;
}

// ---------------------------------------------------------------------------
// Implicit-GEMM 3x3 conv, v8 (wave-staggered taps; v7 barriers reverted).
// Round-7 model: waves stall on lgkmcnt while LDS pipe is only ~51% busy ->
// queue LATENCY, not BW. All 16 waves/CU march the taps in the SAME order
// after each kk barrier, so 16 correlated 4-read bursts pile into the LDS
// queue (depth ~64-96 -> ~800cyc latency >> the 1-tap lookahead window).
// Deeper lookahead is blocked by the 128-reg occupancy cliff, so v8
// DE-CORRELATES instead, at zero register cost:
//   - tap rotation: wave w processes taps (w+u)%9 -> at any instant the 8
//     waves of a block read 8 DIFFERENT taps; LDS demand is spread, queue
//     depth ~/8. Accumulation order change is benign (f32 acc).
//   - stage spread: the 5 per-wave gld_lds for kk+1 issue one-per-tap over
//     taps u=0..4 instead of bursting at kk top (smooths LDS-write traffic).
// Everything else = v6: top-staged W+B dbuf in LDS, single vmcnt(0)+barrier
// per kk, 1-tap LDS lookahead, setprio around the 4-MFMA cluster.
// Block: 64 out-ch x 512 px, 8 waves x 512 thr, wave = 64ch x 64px,
// acc[2][2] = 64 AGPR + ~64 VGPR; LDS 79104 B -> 2 blocks/CU.
// EPI 0: dstH[padded NHWC] = g ? relu(acc) : 0  (g = 3x3 OR mask, fused dil)
// EPI 1: dstF[NCHW fp32]   = xres + (g ? relu(acc):0)  (g = std mask)
// ---------------------------------------------------------------------------
#define BBUF 10560   // shorts per B buffer (2 K-halves x 660 slots x 8)
#define WOFF 21120   // 2 * BBUF
#define WBUF 9216    // shorts per W buffer (9 taps x 2 ihalf x 64 ch x 8)

// Stage inst q (of 5) for k-chunk kc into buffer buf. n = wave + 8q covers
// 22 B insts + 18 W insts (n>39 impossible: q<5, wave<8).
__device__ __forceinline__ void stage_one(short* sm, int buf, const short* Xb,
                                          const short* Wg, int ch0, int kc,
                                          int wave, int lane, int q) {
  const int n = wave + 8 * q;
  const int ko = kc * 16;
  if (n < 22) {
    // B: 11 insts per K-half; inst i<10 covers slots 64i..64i+63, inst 10
    // covers 596..659 (overlaps inst 9, identical bytes -> benign).
    const int h = (n >= 11) ? 1 : 0;
    const int i = n - h * 11;
    const int row0 = (i < 10) ? i * 64 : 596;
    gld_lds16(Xb + (size_t)(row0 + lane) * 256 + ko + h * 8,
              sm + buf * BBUF + h * 5280 + row0 * 8);
  } else {
    // W inst m=n-22: t = m>>1, ihalf = m&1; 64 lanes cover 32 ch x 2 khalf.
    const int m = n - 22;
    const int t = m >> 1, ih = m & 1;
    gld_lds16(Wg + (((size_t)t * 16 + kc) * 256 + ch0 + ih * 32 +
                    (lane & 31)) * 16 + (lane >> 5) * 8,
              sm + WOFF + buf * WBUF + (t * 2 + ih) * 512);
  }
}

template <int EPI>
__global__ __launch_bounds__(512, 4) void conv_mfma(
    const short* __restrict__ src, const short* __restrict__ Wt,
    const unsigned char* __restrict__ gate, const float* __restrict__ xres,
    short* __restrict__ dstH, float* __restrict__ dstF, int swz) {
  __shared__ __align__(16) short sm[2 * BBUF + 2 * WBUF];  // 79104 B

  const int tid = threadIdx.x;
  const int lane = tid & 63, wave = tid >> 6;  // 8 waves
  const int ln31 = lane & 31, kh = lane >> 5;

  // Block decode; swizzled path groups the 4 ch-sibling blocks on one XCD.
  int bx, by, bz;
  {
    int d = blockIdx.x + 4 * (blockIdx.y + 8 * blockIdx.z);
    if (swz) {
      int k = d & 7, j = d >> 3;
      bx = j & 3;
      by = (j >> 2) & 7;
      bz = ((j >> 5) << 3) + k;
    } else {
      bx = blockIdx.x;
      by = blockIdx.y;
      bz = blockIdx.z;
    }
  }
  const int ch0 = bx * 64;
  const int h0 = by * 8;
  const int img = bz;

  const short* Xb = src + (size_t)img * PADIMG_ + (size_t)(h0 * 66) * 256;

  f32x16 acc[2][2];
#pragma unroll
  for (int i = 0; i < 2; ++i)
#pragma unroll
    for (int j = 0; j < 2; ++j)
#pragma unroll
      for (int e = 0; e < 16; ++e) acc[i][j][e] = 0.f;

  // Prologue: stage k-chunk 0 into buf 0 (burst is fine here; nothing to
  // overlap with yet).
#pragma unroll
  for (int q = 0; q < 5; ++q)
    stage_one(sm, 0, Xb, Wt, ch0, 0, wave, lane, q);
  asm volatile("s_waitcnt vmcnt(0)\n\ts_barrier" ::: "memory");

  for (int kk = 0; kk < 16; ++kk) {
    const int cur = kk & 1;
    const short* Bth = sm + cur * BBUF + kh * 5280 + (wave * 66 + ln31) * 8;
    const short* Wth = sm + WOFF + cur * WBUF + (kh * 32 + ln31) * 8;

    bf16x8 ac[2], bc[2], an[2], bn[2];
    {
      // u=0 tap for this wave: tt = wave (wave < 8 < 9).
      const int tt = wave;
      const int dy = (tt * 11) >> 5, dx = tt - 3 * dy;
      const int bo = (dy * 66 + dx) * 8;
      ac[0] = *(const bf16x8*)(Wth + tt * 1024);
      ac[1] = *(const bf16x8*)(Wth + tt * 1024 + 512);
      bc[0] = *(const bf16x8*)(Bth + bo);
      bc[1] = *(const bf16x8*)(Bth + bo + 256);
    }
#pragma unroll
    for (int u = 0; u < 9; ++u) {
      // Spread next-chunk staging across taps 0..4 (1 gld_lds per tap).
      if (u < 5 && kk < 15)
        stage_one(sm, cur ^ 1, Xb, Wt, ch0, kk + 1, wave, lane, u);
      if (u < 8) {  // 1-tap lookahead, rotated tap id
        int tt = wave + u + 1;
        if (tt >= 9) tt -= 9;
        const int dy = (tt * 11) >> 5, dx = tt - 3 * dy;
        const int bo = (dy * 66 + dx) * 8;
        an[0] = *(const bf16x8*)(Wth + tt * 1024);
        an[1] = *(const bf16x8*)(Wth + tt * 1024 + 512);
        bn[0] = *(const bf16x8*)(Bth + bo);
        bn[1] = *(const bf16x8*)(Bth + bo + 256);
      }
      __builtin_amdgcn_s_setprio(1);
      acc[0][0] = __builtin_amdgcn_mfma_f32_32x32x16_bf16(ac[0], bc[0],
                                                          acc[0][0], 0, 0, 0);
      acc[0][1] = __builtin_amdgcn_mfma_f32_32x32x16_bf16(ac[0], bc[1],
                                                          acc[0][1], 0, 0, 0);
      acc[1][0] = __builtin_amdgcn_mfma_f32_32x32x16_bf16(ac[1], bc[0],
                                                          acc[1][0], 0, 0, 0);
      acc[1][1] = __builtin_amdgcn_mfma_f32_32x32x16_bf16(ac[1], bc[1],
                                                          acc[1][1], 0, 0, 0);
      __builtin_amdgcn_s_setprio(0);
      if (u < 8) {
        ac[0] = an[0]; ac[1] = an[1];
        bc[0] = bn[0]; bc[1] = bn[1];
      }
    }
    if (kk < 15)
      asm volatile("s_waitcnt vmcnt(0)\n\ts_barrier" ::: "memory");
  }

  // Epilogue. 32x32 D layout: col(pixel)=lane&31, row(ch)=(reg&3)+8*(reg>>2)
  // +4*(lane>>5)  => reg group rg gives 4 consecutive channels.
  const int r = h0 + wave;
#pragma unroll
  for (int j = 0; j < 2; ++j) {
    const int col = j * 32 + ln31;
    const int pidx = r * 64 + col;
    unsigned int g;
    if (EPI == 0) {
      // fused dilation: 3x3 OR of std mask around (r,col)
      g = 0;
#pragma unroll
      for (int dy = -1; dy <= 1; ++dy) {
        const int rr = r + dy;
        if (rr < 0 || rr >= H_) continue;
#pragma unroll
        for (int dx = -1; dx <= 1; ++dx) {
          const int cc = col + dx;
          if (cc < 0 || cc >= W_) continue;
          g |= gate[img * HW_ + rr * W_ + cc];
        }
      }
    } else {
      g = gate[img * HW_ + pidx];
    }
#pragma unroll
    for (int i = 0; i < 2; ++i) {
      const f32x16 v = acc[i][j];
#pragma unroll
      for (int rg = 0; rg < 4; ++rg) {
        const int ch = ch0 + i * 32 + rg * 8 + kh * 4;
        float e0 = g ? fmaxf(v[rg * 4 + 0], 0.f) : 0.f;
        float e1 = g ? fmaxf(v[rg * 4 + 1], 0.f) : 0.f;
        float e2 = g ? fmaxf(v[rg * 4 + 2], 0.f) : 0.f;
        float e3 = g ? fmaxf(v[rg * 4 + 3], 0.f) : 0.f;
        if (EPI == 0) {
          uint2 u;
          u.x = (unsigned int)f2bf(e0) | ((unsigned int)f2bf(e1) << 16);
          u.y = (unsigned int)f2bf(e2) | ((unsigned int)f2bf(e3) << 16);
          short* dp = dstH + (size_t)img * PADIMG_ +
                      ((size_t)((r + 1) * 66 + (col + 1))) * 256 + ch;
          *(uint2*)dp = u;
        } else {
          size_t o = (size_t)img * IMG_ + (size_t)ch * HW_ + pidx;
          dstF[o] = xres[o] + e0;
          dstF[o + HW_] = xres[o + HW_] + e1;
          dstF[o + 2 * HW_] = xres[o + 2 * HW_] + e2;
          dstF[o + 3 * HW_] = xres[o + 3 * HW_] + e3;
        }
      }
    }
  }
}

// ---------------------------------------------------------------------------
extern "C" void kernel_launch(void* const* d_in, const int* in_sizes, int n_in,
                              void* d_out, int out_size, void* d_ws,
                              size_t ws_size, hipStream_t stream) {
  const float* x = (const float*)d_in[0];
  const float* w1 = (const float*)d_in[1];
  const float* w2 = (const float*)d_in[2];
  const float* wmask = (const float*)d_in[3];
  const float* bmask = (const float*)d_in[4];
  float* out = (float*)d_out;

  char* ws = (char*)d_ws;
  unsigned char* mask = (unsigned char*)ws;  // 64 KB
  short* Wt1 = (short*)(ws + 65536);         // 1.125 MiB
  short* Wt2 = Wt1 + WT_ELEMS_;              // 1.125 MiB
  const size_t fixed = 65536 + 4 * (size_t)WT_ELEMS_;  // mask + 2 Wt (bytes)
  short* Xp = (short*)(ws + fixed);

  const size_t tailpad = 32768;  // safety pad past last image
  const size_t per_img = 2 * (size_t)PADIMG_ * 2;  // Xp + Hp bytes per image
  int B = (ws_size > fixed + tailpad)
              ? (int)((ws_size - fixed - tailpad) / per_img) : 0;
  if (B > N_) B = N_;
  if (B < 1) B = 1;
  short* Hp = Xp + (size_t)B * PADIMG_;

  wt_kernel<<<dim3(256, 2), 256, 0, stream>>>(w1, w2, Wt1, Wt2);
  halo_zero<<<dim3(260, B), 128, 0, stream>>>(Hp);

  for (int n0 = 0; n0 < N_; n0 += B) {
    const int nb = (N_ - n0 < B) ? (N_ - n0) : B;
    const int swz = (nb % 8 == 0) ? 1 : 0;
    xpadmask_kernel<<<dim3(64, nb), 256, 0, stream>>>(
        x + (size_t)n0 * IMG_, wmask, bmask, Xp, mask + n0 * HW_);
    conv_mfma<0><<<dim3(4, 8, nb), 512, 0, stream>>>(
        Xp, Wt1, mask + n0 * HW_, nullptr, Hp, nullptr, swz);
    conv_mfma<1><<<dim3(4, 8, nb), 512, 0, stream>>>(
        Hp, Wt2, mask + n0 * HW_, x + (size_t)n0 * IMG_, nullptr,
        out + (size_t)n0 * IMG_, swz);
  }
}

// Round 9
// 287.159 us; speedup vs baseline: 1.2111x; 1.2111x over previous
//
#include <hip/hip_runtime.h>
#include <hip/hip_bf16.h>

#define C_ 256
#define H_ 64
#define W_ 64
#define N_ 16
#define HW_ 4096
#define IMG_ (C_ * HW_)          // 1048576 elems (fp32 image)
#define PADIMG_ (66 * 66 * 256)  // 1115136 shorts per padded NHWC image
#define WT_ELEMS_ (9 * 16 * 256 * 16)

typedef short bf16x8 __attribute__((ext_vector_type(8)));
typedef float f32x16 __attribute__((ext_vector_type(16)));

__device__ __forceinline__ unsigned short f2bf(float f) {
  __hip_bfloat16 h = __float2bfloat16(f);  // RTNE
  return *reinterpret_cast<unsigned short*>(&h);
}

__device__ __forceinline__ void gld_lds16(const void* g, void* l) {
  __builtin_amdgcn_global_load_lds(
      (const __attribute__((address_space(1))) void*)g,
      (__attribute__((address_space(3))) void*)l, 16, 0, 0);
}

// ---------------------------------------------------------------------------
// Fused x->padded-NHWC-bf16 transform + mask logits (fp64, sign-exact).
// Also zeroes this image's Xp halo (disjoint regions across blocks).
// ---------------------------------------------------------------------------
__global__ __launch_bounds__(256) void xpadmask_kernel(
    const float* __restrict__ x, const float* __restrict__ wm,
    const float* __restrict__ bm, short* __restrict__ Xp,
    unsigned char* __restrict__ mask) {
  __shared__ unsigned short lds[64 * 260];
  __shared__ float wms[256];
  __shared__ double sums[4][64];
  const int h = blockIdx.x, img = blockIdx.y;
  const int tid = threadIdx.x;
  const int wv = tid >> 6, wl = tid & 63;
  wms[tid] = wm[tid];
  __syncthreads();
  const float* xi = x + (size_t)img * IMG_ + h * 64;
  double a0 = 0.0, a1 = 0.0, a2 = 0.0, a3 = 0.0;
#pragma unroll 4
  for (int i = 0; i < 16; ++i) {
#pragma unroll
    for (int u = 0; u < 4; ++u) {
      int c = (i * 4 + u) * 4 + wv;
      float v = xi[(size_t)c * HW_ + wl];
      lds[wl * 260 + c] = f2bf(v);
      double p = (double)v * (double)wms[c];
      if (u == 0) a0 += p;
      else if (u == 1) a1 += p;
      else if (u == 2) a2 += p;
      else a3 += p;
    }
  }
  sums[wv][wl] = (a0 + a1) + (a2 + a3);
  __syncthreads();
  short* Xpimg = Xp + (size_t)img * PADIMG_;
  short* Xpi = Xpimg + ((h + 1) * 66 + 1) * 256;
#pragma unroll
  for (int j = 0; j < 16; ++j) {
    int w = j * 4 + wv;
    int c4 = wl * 4;
    uint2 d = *(const uint2*)&lds[w * 260 + c4];
    *(uint2*)&Xpi[(size_t)w * 256 + c4] = d;
  }
  // Xp halo: left/right columns of this padded row.
  if (tid < 128) {
    const int side = tid >> 6;    // 0 -> col 0, 1 -> col 65
    const int e = (tid & 63) * 4;
    *(uint2*)&Xpimg[((size_t)(h + 1) * 66 + side * 65) * 256 + e] =
        make_uint2(0u, 0u);
  }
  // Xp halo: full top/bottom padded rows.
  if (h == 0 || h == 63) {
    uint2* rowp = (uint2*)(Xpimg + (size_t)((h == 0) ? 0 : 65) * 66 * 256);
    for (int o = tid; o < 66 * 256 / 4; o += 256) rowp[o] = make_uint2(0u, 0u);
  }
  if (wv == 0) {
    double t = sums[0][wl] + sums[1][wl] + sums[2][wl] + sums[3][wl] +
               (double)bm[0];
    mask[img * HW_ + h * 64 + wl] = (t > 0.0) ? 1 : 0;
  }
}

// ---------------------------------------------------------------------------
// Weight transform: Wt[t][kc][k][c16] = bf16(w[k][kc*16+c16][t])
// ---------------------------------------------------------------------------
__global__ __launch_bounds__(256) void wt_kernel(
    const float* __restrict__ w1, const float* __restrict__ w2,
    short* __restrict__ Wt1, short* __restrict__ Wt2) {
  const int k = blockIdx.x, c = threadIdx.x;
  const float* src = blockIdx.y ? w2 : w1;
  short* dst = blockIdx.y ? Wt2 : Wt1;
  const float* s = src + ((size_t)k * 256 + c) * 9;
  const int kc = c >> 4, ce = c & 15;
#pragma unroll
  for (int t = 0; t < 9; ++t)
    dst[(((size_t)t * 16 + kc) * 256 + k) * 16 + ce] = (short)f2bf(s[t]);
}

// ---------------------------------------------------------------------------
// Zero the padded halo (rows 0,65; cols 0,65) of Hp (Xp handled in xpadmask).
// ---------------------------------------------------------------------------
__global__ __launch_bounds__(128) void halo_zero(short* __restrict__ Hp) {
  int p = blockIdx.x;  // 0..259 halo pixel id
  int r, c;
  if (p < 66) { r = 0; c = p; }
  else if (p < 132) { r = 65; c = p - 66; }
  else if (p < 196) { r = p - 131; c = 0; }
  else { r = p - 195; c = 65; }
  unsigned int* d = (unsigned int*)(Hp + (size_t)blockIdx.y * PADIMG_ +
                                    (size_t)(r * 66 + c) * 256);
  d[threadIdx.x] = 0u;
}

// ---------------------------------------------------------------------------
// Implicit-GEMM 3x3 conv, v9 (fat accumulator x pipelined LDS staging).
// Round-8 stock-take: v6's 4-read:4-MFMA ratio makes LDS reads (576/kk/CU =
// ~6.9K cyc) the binding pipe above the matrix floor (4.65K); v2's acc[2][4]
// had the right 6:8 ratio (432 reads = 5.2K, balanced) but a drain-stalled
// 2-phase structure. v9 = the untested cell: fat acc + v6's pipeline.
//   Block: 64 out-ch x 512 px (8 rows x 64 cols), 4 waves x 256 thr,
//   wave owns 2 rows (128 px): acc[2 ch][4 px] = 128 AGPR, ~90 VGPR ->
//   2 waves/SIMD, 2 blocks/CU. Per tap: 2 a-reads + 4 b-reads -> 8 MFMA.
//   Compute phase has ZERO vmem deps (W+B both LDS, v4's failure mode gone);
//   only the 1-tap lgkm chain must be covered by the 2-wave ping-pong.
// LDS identical to v6 (79104 B): B dbuf 2x21120 B + W dbuf 2x18432 B.
// Staging: 40 gld_lds16 per block at kk top (10 per wave, vmcnt-symmetric);
// single end-of-kk vmcnt(0)+s_barrier (loads issued a full compute earlier).
// All LDS offsets compile-time (v8 lesson: runtime offsets wreck codegen).
// EPI 0: dstH[padded NHWC] = g ? relu(acc) : 0  (g = 3x3 OR mask, fused dil)
// EPI 1: dstF[NCHW fp32]   = xres + (g ? relu(acc):0)  (g = std mask)
// ---------------------------------------------------------------------------
#define BBUF 10560   // shorts per B buffer (2 K-halves x 660 slots x 8)
#define WOFF 21120   // 2 * BBUF
#define WBUF 9216    // shorts per W buffer (9 taps x 2 ihalf x 64 ch x 8)

// Stage B(22 insts) + W(18 insts) for k-chunk kc into buffer buf.
// Wave w (of 4) issues insts n = w, w+4, .., w+36 (exactly 10 each).
__device__ __forceinline__ void stage_BW(short* sm, int buf, const short* Xb,
                                         const short* Wg, int ch0, int kc,
                                         int wave, int lane) {
  short* Bd = sm + buf * BBUF;
  short* Wd = sm + WOFF + buf * WBUF;
  const int ko = kc * 16;
#pragma unroll
  for (int q = 0; q < 10; ++q) {
    const int n = wave + 4 * q;
    if (n < 22) {
      // B: 11 insts per K-half; inst i<10 covers slots 64i..64i+63, inst 10
      // covers 596..659 (overlaps inst 9, identical bytes -> benign).
      const int h = (n >= 11) ? 1 : 0;
      const int i = n - h * 11;
      const int row0 = (i < 10) ? i * 64 : 596;
      gld_lds16(Xb + (size_t)(row0 + lane) * 256 + ko + h * 8,
                Bd + h * 5280 + row0 * 8);
    } else {
      // W inst m=n-22: t = m>>1, ihalf = m&1; 64 lanes cover 32 ch x 2 khalf.
      const int m = n - 22;
      const int t = m >> 1, ih = m & 1;
      gld_lds16(Wg + (((size_t)t * 16 + kc) * 256 + ch0 + ih * 32 +
                      (lane & 31)) * 16 + (lane >> 5) * 8,
                Wd + (t * 2 + ih) * 512);
    }
  }
}

template <int EPI>
__global__ __launch_bounds__(256, 2) void conv_mfma(
    const short* __restrict__ src, const short* __restrict__ Wt,
    const unsigned char* __restrict__ gate, const float* __restrict__ xres,
    short* __restrict__ dstH, float* __restrict__ dstF, int swz) {
  __shared__ __align__(16) short sm[2 * BBUF + 2 * WBUF];  // 79104 B

  const int tid = threadIdx.x;
  const int lane = tid & 63, wave = tid >> 6;  // 4 waves
  const int ln31 = lane & 31, kh = lane >> 5;

  // Block decode; swizzled path groups the 4 ch-sibling blocks on one XCD.
  int bx, by, bz;
  {
    int d = blockIdx.x + 4 * (blockIdx.y + 8 * blockIdx.z);
    if (swz) {
      int k = d & 7, j = d >> 3;
      bx = j & 3;
      by = (j >> 2) & 7;
      bz = ((j >> 5) << 3) + k;
    } else {
      bx = blockIdx.x;
      by = blockIdx.y;
      bz = blockIdx.z;
    }
  }
  const int ch0 = bx * 64;
  const int h0 = by * 8;
  const int img = bz;

  const short* Xb = src + (size_t)img * PADIMG_ + (size_t)(h0 * 66) * 256;

  f32x16 acc[2][4];
#pragma unroll
  for (int i = 0; i < 2; ++i)
#pragma unroll
    for (int j = 0; j < 4; ++j)
#pragma unroll
      for (int e = 0; e < 16; ++e) acc[i][j][e] = 0.f;

  // Prologue: stage k-chunk 0 into buf 0.
  stage_BW(sm, 0, Xb, Wt, ch0, 0, wave, lane);
  asm volatile("s_waitcnt vmcnt(0)\n\ts_barrier" ::: "memory");

  for (int kk = 0; kk < 16; ++kk) {
    const int cur = kk & 1;
    // Stage next k-chunk; latency hides under this kk's pure-LDS compute.
    if (kk < 15) stage_BW(sm, cur ^ 1, Xb, Wt, ch0, kk + 1, wave, lane);

    // Per-thread read bases (compile-time offsets from here on).
    // Wave owns padded rows wave*2 + (j>>1) + dy, cols (j&1)*32 + dx.
    const short* Bth = sm + cur * BBUF + kh * 5280 + (wave * 132 + ln31) * 8;
    const short* Wth = sm + WOFF + cur * WBUF + (kh * 32 + ln31) * 8;

    bf16x8 ac[2], bc[4], an[2], bn[4];
#pragma unroll
    for (int i = 0; i < 2; ++i)  // tap 0 frags
      ac[i] = *(const bf16x8*)(Wth + i * 512);
#pragma unroll
    for (int j = 0; j < 4; ++j)
      bc[j] = *(const bf16x8*)(Bth + ((j >> 1) * 66 + (j & 1) * 32) * 8);

#pragma unroll
    for (int t = 0; t < 9; ++t) {
      if (t < 8) {  // 1-tap lookahead (pure LDS, compile-time offsets)
        const int dy = (t + 1) / 3, dx = (t + 1) % 3;
#pragma unroll
        for (int i = 0; i < 2; ++i)
          an[i] = *(const bf16x8*)(Wth + ((t + 1) * 2 + i) * 512);
#pragma unroll
        for (int j = 0; j < 4; ++j)
          bn[j] = *(const bf16x8*)(Bth +
                                   (((j >> 1) + dy) * 66 + (j & 1) * 32 + dx) * 8);
      }
      __builtin_amdgcn_s_setprio(1);
#pragma unroll
      for (int j = 0; j < 4; ++j) {
        acc[0][j] = __builtin_amdgcn_mfma_f32_32x32x16_bf16(ac[0], bc[j],
                                                            acc[0][j], 0, 0, 0);
        acc[1][j] = __builtin_amdgcn_mfma_f32_32x32x16_bf16(ac[1], bc[j],
                                                            acc[1][j], 0, 0, 0);
      }
      __builtin_amdgcn_s_setprio(0);
      if (t < 8) {
#pragma unroll
        for (int i = 0; i < 2; ++i) ac[i] = an[i];
#pragma unroll
        for (int j = 0; j < 4; ++j) bc[j] = bn[j];
      }
    }
    if (kk < 15)
      asm volatile("s_waitcnt vmcnt(0)\n\ts_barrier" ::: "memory");
  }

  // Epilogue. 32x32 D layout: col(pixel)=lane&31, row(ch)=(reg&3)+8*(reg>>2)
  // +4*(lane>>5)  => reg group rg gives 4 consecutive channels.
  const int rb = h0 + wave * 2;
#pragma unroll
  for (int j = 0; j < 4; ++j) {
    const int r = rb + (j >> 1);
    const int col = (j & 1) * 32 + ln31;
    const int pidx = r * 64 + col;
    unsigned int g;
    if (EPI == 0) {
      // fused dilation: 3x3 OR of std mask around (r,col)
      g = 0;
#pragma unroll
      for (int dy = -1; dy <= 1; ++dy) {
        const int rr = r + dy;
        if (rr < 0 || rr >= H_) continue;
#pragma unroll
        for (int dx = -1; dx <= 1; ++dx) {
          const int cc = col + dx;
          if (cc < 0 || cc >= W_) continue;
          g |= gate[img * HW_ + rr * W_ + cc];
        }
      }
    } else {
      g = gate[img * HW_ + pidx];
    }
#pragma unroll
    for (int i = 0; i < 2; ++i) {
      const f32x16 v = acc[i][j];
#pragma unroll
      for (int rg = 0; rg < 4; ++rg) {
        const int ch = ch0 + i * 32 + rg * 8 + kh * 4;
        float e0 = g ? fmaxf(v[rg * 4 + 0], 0.f) : 0.f;
        float e1 = g ? fmaxf(v[rg * 4 + 1], 0.f) : 0.f;
        float e2 = g ? fmaxf(v[rg * 4 + 2], 0.f) : 0.f;
        float e3 = g ? fmaxf(v[rg * 4 + 3], 0.f) : 0.f;
        if (EPI == 0) {
          uint2 u;
          u.x = (unsigned int)f2bf(e0) | ((unsigned int)f2bf(e1) << 16);
          u.y = (unsigned int)f2bf(e2) | ((unsigned int)f2bf(e3) << 16);
          short* dp = dstH + (size_t)img * PADIMG_ +
                      ((size_t)((r + 1) * 66 + (col + 1))) * 256 + ch;
          *(uint2*)dp = u;
        } else {
          size_t o = (size_t)img * IMG_ + (size_t)ch * HW_ + pidx;
          dstF[o] = xres[o] + e0;
          dstF[o + HW_] = xres[o + HW_] + e1;
          dstF[o + 2 * HW_] = xres[o + 2 * HW_] + e2;
          dstF[o + 3 * HW_] = xres[o + 3 * HW_] + e3;
        }
      }
    }
  }
}

// ---------------------------------------------------------------------------
extern "C" void kernel_launch(void* const* d_in, const int* in_sizes, int n_in,
                              void* d_out, int out_size, void* d_ws,
                              size_t ws_size, hipStream_t stream) {
  const float* x = (const float*)d_in[0];
  const float* w1 = (const float*)d_in[1];
  const float* w2 = (const float*)d_in[2];
  const float* wmask = (const float*)d_in[3];
  const float* bmask = (const float*)d_in[4];
  float* out = (float*)d_out;

  char* ws = (char*)d_ws;
  unsigned char* mask = (unsigned char*)ws;  // 64 KB
  short* Wt1 = (short*)(ws + 65536);         // 1.125 MiB
  short* Wt2 = Wt1 + WT_ELEMS_;              // 1.125 MiB
  const size_t fixed = 65536 + 4 * (size_t)WT_ELEMS_;  // mask + 2 Wt (bytes)
  short* Xp = (short*)(ws + fixed);

  const size_t tailpad = 32768;  // safety pad past last image
  const size_t per_img = 2 * (size_t)PADIMG_ * 2;  // Xp + Hp bytes per image
  int B = (ws_size > fixed + tailpad)
              ? (int)((ws_size - fixed - tailpad) / per_img) : 0;
  if (B > N_) B = N_;
  if (B < 1) B = 1;
  short* Hp = Xp + (size_t)B * PADIMG_;

  wt_kernel<<<dim3(256, 2), 256, 0, stream>>>(w1, w2, Wt1, Wt2);
  halo_zero<<<dim3(260, B), 128, 0, stream>>>(Hp);

  for (int n0 = 0; n0 < N_; n0 += B) {
    const int nb = (N_ - n0 < B) ? (N_ - n0) : B;
    const int swz = (nb % 8 == 0) ? 1 : 0;
    xpadmask_kernel<<<dim3(64, nb), 256, 0, stream>>>(
        x + (size_t)n0 * IMG_, wmask, bmask, Xp, mask + n0 * HW_);
    conv_mfma<0><<<dim3(4, 8, nb), 256, 0, stream>>>(
        Xp, Wt1, mask + n0 * HW_, nullptr, Hp, nullptr, swz);
    conv_mfma<1><<<dim3(4, 8, nb), 256, 0, stream>>>(
        Hp, Wt2, mask + n0 * HW_, x + (size_t)n0 * IMG_, nullptr,
        out + (size_t)n0 * IMG_, swz);
  }
}